// Round 2
// baseline (23042.529 us; speedup 1.0000x reference)
//
#include <hip/hip_runtime.h>

typedef unsigned short u16;
typedef __attribute__((ext_vector_type(8))) short short8;
typedef __attribute__((ext_vector_type(4))) short short4v;
typedef __attribute__((ext_vector_type(4))) float f32x4;

#define B_    64
#define S_    512
#define E_    512
#define H_    512
#define NSEG_ 64

// ---------- helpers ----------
__device__ __forceinline__ float bf2f(u16 u) {
    union { unsigned int i; float f; } x; x.i = ((unsigned int)u) << 16; return x.f;
}
__device__ __forceinline__ u16 f2bf(float f) {
    union { float f; unsigned int i; } x; x.f = f;
    unsigned int r = x.i + 0x7fffu + ((x.i >> 16) & 1u);
    return (u16)(r >> 16);
}
__device__ __forceinline__ f32x4 mfma16(short8 a, short8 b, f32x4 c) {
    return __builtin_amdgcn_mfma_f32_16x16x32_bf16(a, b, c, 0, 0, 0);
}
__device__ __forceinline__ float sigmoidf_(float x) { return 1.f / (1.f + __expf(-x)); }
__device__ __forceinline__ float tanhf_(float x) {
    float e = __expf(-2.f * fabsf(x));
    float t = (1.f - e) / (1.f + e);
    return x < 0.f ? -t : t;
}
__device__ __forceinline__ u16 u2_get(uint2 v, int i) {
    const unsigned x = (i < 2) ? v.x : v.y;
    return (u16)(x >> ((i & 1) * 16));
}

// workspace layout (bytes)
#define EMBB_OFF  0
#define WIHB_OFF  51200000
#define WHHB_OFF  54345728
#define XP_OFF    57757696

// ---------- prep: fp32 -> bf16 conversions ----------
__global__ __launch_bounds__(256) void prep_kernel(
    const float* __restrict__ emb,
    const float* __restrict__ wih_f, const float* __restrict__ whh_f,
    const float* __restrict__ wih_b, const float* __restrict__ whh_b,
    u16* __restrict__ embb, u16* __restrict__ wihbb, u16* __restrict__ whhbb)
{
    const int nt = gridDim.x * 256;
    const int i = blockIdx.x * 256 + threadIdx.x;

    const float4* e4 = (const float4*)emb;
    short4v* eo = (short4v*)embb;
    for (int k = i; k < 6400000; k += nt) {
        float4 v = e4[k];
        short4v o = { (short)f2bf(v.x), (short)f2bf(v.y), (short)f2bf(v.z), (short)f2bf(v.w) };
        eo[k] = o;
    }
    const float4* wf[4] = { (const float4*)wih_f, (const float4*)wih_b,
                            (const float4*)whh_f, (const float4*)whh_b };
    short4v* wo[4] = { (short4v*)wihbb, (short4v*)(wihbb + 786432),
                       (short4v*)whhbb, (short4v*)(whhbb + 786432) };
#pragma unroll
    for (int a = 0; a < 4; ++a) {
        for (int k = i; k < 196608; k += nt) {
            float4 v = wf[a][k];
            short4v o = { (short)f2bf(v.x), (short)f2bf(v.y), (short)f2bf(v.z), (short)f2bf(v.w) };
            wo[a][k] = o;
        }
    }
}

// ---------- input projection: xp = emb[seq] @ w_ih_d^T + b_ih_d (+ b_hh r/z) ----------
// New xp layout for the workgroup-local rnn:
//   slab = (dir*4 + group)*16 + wave   (128 slabs)
//   idx within slab = ((pos*16 + sample_in_group)*3 + gate)*32 + u_local
// so each rnn wave reads 6 contiguous 8B chunks per step.
// r/z gates get b_hh folded in here (saves registers + VALU in the rnn).
__global__ __launch_bounds__(256) void proj_kernel(
    const int* __restrict__ seq, const u16* __restrict__ embb,
    const u16* __restrict__ wihbb,
    const float* __restrict__ b_ih_f, const float* __restrict__ b_ih_b,
    const float* __restrict__ b_hh_f, const float* __restrict__ b_hh_b,
    u16* __restrict__ xp)
{
    const int bid = blockIdx.x;            // 256 * 24
    const int mt = bid / 24, nt = bid % 24;
    const int tid = threadIdx.x;
    const int w = tid >> 6, l = tid & 63;
    const int q = l >> 4, col = l & 15;
    const int M0 = mt * 128 + (w >> 1) * 64;
    const int N0 = nt * 128 + (w & 1) * 64;

    const u16* arow[4];
#pragma unroll
    for (int ai = 0; ai < 4; ++ai) {
        const int tok = seq[M0 + ai * 16 + col];
        arow[ai] = embb + (long)tok * E_;
    }
    const u16* brow[4];
#pragma unroll
    for (int bi = 0; bi < 4; ++bi)
        brow[bi] = wihbb + (long)(N0 + bi * 16 + col) * E_;

    f32x4 acc[4][4];
#pragma unroll
    for (int ai = 0; ai < 4; ++ai)
#pragma unroll
        for (int bi = 0; bi < 4; ++bi) acc[ai][bi] = (f32x4){0,0,0,0};

    for (int k = 0; k < 16; ++k) {
        const int ko = k * 32 + q * 8;
        short8 a[4], b[4];
#pragma unroll
        for (int ai = 0; ai < 4; ++ai) a[ai] = *(const short8*)(arow[ai] + ko);
#pragma unroll
        for (int bi = 0; bi < 4; ++bi) b[bi] = *(const short8*)(brow[bi] + ko);
#pragma unroll
        for (int ai = 0; ai < 4; ++ai)
#pragma unroll
            for (int bi = 0; bi < 4; ++bi)
                acc[ai][bi] = mfma16(a[ai], b[bi], acc[ai][bi]);
    }

#pragma unroll
    for (int bi = 0; bi < 4; ++bi) {
        const int n = N0 + bi * 16 + col;
        const int dir = (n >= 1536) ? 1 : 0;
        const int j = n - dir * 1536;
        const int gg = j >> 9, u = j & 511;
        const int wv = u >> 5, ul = u & 31;
        float bias = dir ? b_ih_b[j] : b_ih_f[j];
        if (gg < 2) bias += dir ? b_hh_b[j] : b_hh_f[j];   // fold r/z recurrent bias
#pragma unroll
        for (int ai = 0; ai < 4; ++ai) {
#pragma unroll
            for (int i = 0; i < 4; ++i) {
                const int m = M0 + ai * 16 + q * 4 + i;
                const int bs = m >> 9, s = m & 511;
                const int g = bs >> 4, sb = bs & 15;
                const long slab = (long)((dir * 4 + g) * 16 + wv);
                xp[((slab * 512 + s) * 16 + sb) * 96 + gg * 32 + ul] =
                    f2bf(acc[ai][bi][i] + bias);
            }
        }
    }
}

// ---------- recurrence + fused segment max (workgroup-local, LDS exchange) ----------
// 8 blocks x 1024 threads. Block = (dir, group-of-16-samples) domain.
// 16 waves/block; wave w owns u-cols [w*32, w*32+32) x 3 gates = 96 W_hh rows,
// held permanently in registers (384 VGPR). h (16 samples x 512, bf16) lives in
// LDS, double-buffered; one __syncthreads per step. Lane (q,col): sample = col,
// u = w*32 + s*16 + q*4 + i  (s in {0,1}, i in 0..3).
// LDS h layout: byte = sample*1024 + ((2*u) ^ ((sample&7)<<4))  — XOR swizzle
// kills the 1KB-stride bank conflict on ds_read_b128 (read uses same XOR).
__global__ __launch_bounds__(1024) void rnn_kernel(
    const int* __restrict__ lens, const int* __restrict__ layout,
    const u16* __restrict__ whhbb,
    const float* __restrict__ b_hh_f, const float* __restrict__ b_hh_b,
    const u16* __restrict__ xp, float* __restrict__ out)
{
    const int dmn = blockIdx.x;            // 0..7
    const int dir = dmn >> 2, g = dmn & 3;
    const int w = threadIdx.x >> 6;        // wave 0..15
    const int l = threadIdx.x & 63;
    const int q = l >> 4, col = l & 15;

    __shared__ __align__(16) u16 hls[2][16 * 512];   // 32 KiB

    // zero buf0 (h_{-1} = 0)
    {
        int* p0 = (int*)&hls[0][0];
        for (int k = threadIdx.x; k < 16 * 512 / 2; k += 1024) p0[k] = 0;
    }

    // preload W_hh fragments: 6 m-tiles (gate gg = mt>>1, sub s = mt&1) x 16 ksteps
    const u16* Whh = whhbb + (long)dir * (3 * H_ * H_);
    short8 wreg[6][16];
#pragma unroll
    for (int mt = 0; mt < 6; ++mt) {
        const int gg = mt >> 1, s = mt & 1;
        const u16* wr = Whh + (long)(gg * 512 + w * 32 + s * 16 + col) * H_;
#pragma unroll
        for (int k0 = 0; k0 < 16; ++k0)
            wreg[mt][k0] = *(const short8*)(wr + k0 * 32 + q * 8);
    }

    // n-gate recurrent bias (r/z folded into xp at proj time)
    const float* bhh = dir ? b_hh_b : b_hh_f;
    float bhn[2][4];
#pragma unroll
    for (int s = 0; s < 2; ++s)
#pragma unroll
        for (int i = 0; i < 4; ++i)
            bhn[s][i] = bhh[2 * 512 + w * 32 + s * 16 + q * 4 + i];

    // per-lane sample state (sample = col)
    const int sample = g * 16 + col;
    const int L = lens[sample];
    int seg, bnd;
    if (dir == 0) { seg = 0;  bnd = layout[sample * 65 + 1]; }
    else          { seg = 63; bnd = layout[sample * 65 + 63]; }
    bool done = false;
    float hm[2][4], mx[2][4];
#pragma unroll
    for (int s = 0; s < 2; ++s)
#pragma unroll
        for (int i = 0; i < 4; ++i) { hm[s][i] = 0.f; mx[s][i] = -3.4e38f; }

    const u16* xpb = xp + (long)((dir * 4 + g) * 16 + w) * (512L * 16 * 96);
    const int swz = (col & 7) << 4;
    const int ubase = w * 32;              // wave's first u-col

    __syncthreads();

    for (int t = 0; t < 512; ++t) {
        const int cur = t & 1;
        const bool cval = (t < L);
        int p = dir ? (L - 1 - t) : t;
        if (p < 0) p = 0;

        // ---- segment flush for maxes accumulated through t-1 (off critical path) ----
        if (cval) {
            if (dir == 0) {
                while (t >= bnd && seg < 63) {
#pragma unroll
                    for (int s = 0; s < 2; ++s) {
                        float4 v = { mx[s][0], mx[s][1], mx[s][2], mx[s][3] };
                        *(float4*)(out + ((long)sample * 64 + seg) * 1024 + ubase + s * 16 + q * 4) = v;
                        mx[s][0] = mx[s][1] = mx[s][2] = mx[s][3] = -3.4e38f;
                    }
                    seg++;
                    bnd = layout[sample * 65 + seg + 1];
                }
            } else {
                while (p < bnd && seg > 0) {
#pragma unroll
                    for (int s = 0; s < 2; ++s) {
                        float4 v = { mx[s][0], mx[s][1], mx[s][2], mx[s][3] };
                        *(float4*)(out + ((long)sample * 64 + seg) * 1024 + 512 + ubase + s * 16 + q * 4) = v;
                        mx[s][0] = mx[s][1] = mx[s][2] = mx[s][3] = -3.4e38f;
                    }
                    seg--;
                    bnd = layout[sample * 65 + seg];
                }
            }
        } else if (!done) {
#pragma unroll
            for (int s = 0; s < 2; ++s) {
                float4 v = { mx[s][0], mx[s][1], mx[s][2], mx[s][3] };
                *(float4*)(out + ((long)sample * 64 + seg) * 1024 + dir * 512 + ubase + s * 16 + q * 4) = v;
            }
            done = true;
        }

        // ---- xp loads for this step (global, L2/L3; latency hides under MFMA) ----
        const u16* xq = xpb + ((long)p * 16 + col) * 96;
        uint2 xv[3][2];
#pragma unroll
        for (int gg = 0; gg < 3; ++gg)
#pragma unroll
            for (int s = 0; s < 2; ++s)
                xv[gg][s] = *(const uint2*)(xq + gg * 32 + s * 16 + q * 4);

        // ---- gh = W_hh @ h^T : stream h B-frags from LDS, weights in regs ----
        f32x4 acc[6];
#pragma unroll
        for (int mt = 0; mt < 6; ++mt) acc[mt] = (f32x4){0, 0, 0, 0};
        const char* hb = (const char*)&hls[cur][0];
#pragma unroll
        for (int k0 = 0; k0 < 16; ++k0) {
            const int off = col * 1024 + ((k0 * 64 + q * 16) ^ swz);
            short8 hf = *(const short8*)(hb + off);
#pragma unroll
            for (int mt = 0; mt < 6; ++mt)
                acc[mt] = mfma16(wreg[mt][k0], hf, acc[mt]);
        }

        // ---- gates + state update; update running segment max inline ----
#pragma unroll
        for (int s = 0; s < 2; ++s) {
#pragma unroll
            for (int i = 0; i < 4; ++i) {
                const float xr = bf2f(u2_get(xv[0][s], i));
                const float xz = bf2f(u2_get(xv[1][s], i));
                const float xn = bf2f(u2_get(xv[2][s], i));
                const float r = sigmoidf_(xr + acc[0 + s][i]);
                const float z = sigmoidf_(xz + acc[2 + s][i]);
                const float nn = tanhf_(xn + r * (acc[4 + s][i] + bhn[s][i]));
                const float hv = (1.f - z) * nn + z * hm[s][i];
                if (cval) {
                    hm[s][i] = hv;
                    mx[s][i] = fmaxf(mx[s][i], hv);
                }
            }
        }

        // ---- write h (frozen past L) to the other LDS buffer, swizzled ----
        char* ho = (char*)&hls[cur ^ 1][0];
#pragma unroll
        for (int s = 0; s < 2; ++s) {
            const int off = col * 1024 + (((ubase + s * 16 + q * 4) * 2) ^ swz);
            uint2 pk;
            pk.x = ((unsigned)f2bf(hm[s][1]) << 16) | (unsigned)f2bf(hm[s][0]);
            pk.y = ((unsigned)f2bf(hm[s][3]) << 16) | (unsigned)f2bf(hm[s][2]);
            *(uint2*)(ho + off) = pk;
        }

        __syncthreads();
    }

    // final flush: last partial segment (full-length samples) + final hidden
    if (!done) {
#pragma unroll
        for (int s = 0; s < 2; ++s) {
            float4 v = { mx[s][0], mx[s][1], mx[s][2], mx[s][3] };
            *(float4*)(out + ((long)sample * 64 + seg) * 1024 + dir * 512 + ubase + s * 16 + q * 4) = v;
        }
    }
#pragma unroll
    for (int s = 0; s < 2; ++s) {
        float4 v = { hm[s][0], hm[s][1], hm[s][2], hm[s][3] };
        *(float4*)(out + 4194304 + dir * (B_ * H_) + sample * H_ + ubase + s * 16 + q * 4) = v;
    }
}

// ---------- launch ----------
extern "C" void kernel_launch(void* const* d_in, const int* in_sizes, int n_in,
                              void* d_out, int out_size, void* d_ws, size_t ws_size,
                              hipStream_t stream) {
    const int*   seq    = (const int*)d_in[0];
    const int*   lens   = (const int*)d_in[1];
    const int*   layout = (const int*)d_in[3];
    const float* emb    = (const float*)d_in[4];
    const float* w_ih_f = (const float*)d_in[5];
    const float* w_hh_f = (const float*)d_in[6];
    const float* b_ih_f = (const float*)d_in[7];
    const float* b_hh_f = (const float*)d_in[8];
    const float* w_ih_b = (const float*)d_in[9];
    const float* w_hh_b = (const float*)d_in[10];
    const float* b_ih_b = (const float*)d_in[11];
    const float* b_hh_b = (const float*)d_in[12];
    float* out = (float*)d_out;
    char* ws = (char*)d_ws;

    u16* embb  = (u16*)(ws + EMBB_OFF);
    u16* wihbb = (u16*)(ws + WIHB_OFF);
    u16* whhbb = (u16*)(ws + WHHB_OFF);
    u16* xp    = (u16*)(ws + XP_OFF);

    prep_kernel<<<2048, 256, 0, stream>>>(emb, w_ih_f, w_hh_f, w_ih_b, w_hh_b,
                                          embb, wihbb, whhbb);
    proj_kernel<<<256 * 24, 256, 0, stream>>>(seq, embb, wihbb, b_ih_f, b_ih_b,
                                              b_hh_f, b_hh_b, xp);
    rnn_kernel<<<8, 1024, 0, stream>>>(lens, layout, whhbb, b_hh_f, b_hh_b,
                                       xp, out);
}

// Round 4
// 2340.550 us; speedup vs baseline: 9.8449x; 9.8449x over previous
//
#include <hip/hip_runtime.h>

typedef unsigned short u16;
typedef __attribute__((ext_vector_type(8))) short short8;
typedef __attribute__((ext_vector_type(4))) short short4v;
typedef __attribute__((ext_vector_type(4))) float f32x4;

#define B_    64
#define S_    512
#define E_    512
#define H_    512
#define NSEG_ 64

// ---------- helpers ----------
__device__ __forceinline__ float bf2f(u16 u) {
    union { unsigned int i; float f; } x; x.i = ((unsigned int)u) << 16; return x.f;
}
__device__ __forceinline__ u16 f2bf(float f) {
    union { float f; unsigned int i; } x; x.f = f;
    unsigned int r = x.i + 0x7fffu + ((x.i >> 16) & 1u);
    return (u16)(r >> 16);
}
__device__ __forceinline__ f32x4 mfma16(short8 a, short8 b, f32x4 c) {
    return __builtin_amdgcn_mfma_f32_16x16x32_bf16(a, b, c, 0, 0, 0);
}
__device__ __forceinline__ float sigmoidf_(float x) { return 1.f / (1.f + __expf(-x)); }
__device__ __forceinline__ float tanhf_(float x) {
    float e = __expf(-2.f * fabsf(x));
    float t = (1.f - e) / (1.f + e);
    return x < 0.f ? -t : t;
}

// workspace layout (bytes) — all inputs are FP32; bf16 copies live in ws.
#define EMBB_OFF  0
#define WIHB_OFF  51200000
#define WHHB_OFF  54345728
#define HBUF_OFF  57491456
#define CNT_OFF   57753600
#define XP_OFF    57757696

// ---------- prep: fp32 -> bf16 conversions + zero hbuf/flags ----------
__global__ __launch_bounds__(256) void prep_kernel(
    const float* __restrict__ emb,
    const float* __restrict__ wih_f, const float* __restrict__ whh_f,
    const float* __restrict__ wih_b, const float* __restrict__ whh_b,
    u16* __restrict__ embb, u16* __restrict__ wihbb, u16* __restrict__ whhbb,
    u16* __restrict__ hbuf, int* __restrict__ cnt)
{
    const int nt = gridDim.x * 256;
    const int i = blockIdx.x * 256 + threadIdx.x;

    const float4* e4 = (const float4*)emb;
    short4v* eo = (short4v*)embb;
    for (int k = i; k < 6400000; k += nt) {
        float4 v = e4[k];
        short4v o = { (short)f2bf(v.x), (short)f2bf(v.y), (short)f2bf(v.z), (short)f2bf(v.w) };
        eo[k] = o;
    }
    const float4* wf[4] = { (const float4*)wih_f, (const float4*)wih_b,
                            (const float4*)whh_f, (const float4*)whh_b };
    short4v* wo[4] = { (short4v*)wihbb, (short4v*)(wihbb + 786432),
                       (short4v*)whhbb, (short4v*)(whhbb + 786432) };
#pragma unroll
    for (int a = 0; a < 4; ++a) {
        for (int k = i; k < 196608; k += nt) {
            float4 v = wf[a][k];
            short4v o = { (short)f2bf(v.x), (short)f2bf(v.y), (short)f2bf(v.z), (short)f2bf(v.w) };
            wo[a][k] = o;
        }
    }
    int* hz = (int*)hbuf;
    for (int k = i; k < 65536; k += nt) hz[k] = 0;
    for (int k = i; k < 1024; k += nt) cnt[k] = 0;
}

// ---------- input projection: xp = emb[seq] @ w_ih_d^T + b_ih_d ----------
__global__ __launch_bounds__(256) void proj_kernel(
    const int* __restrict__ seq, const u16* __restrict__ embb,
    const u16* __restrict__ wihbb,
    const float* __restrict__ b_ih_f, const float* __restrict__ b_ih_b,
    u16* __restrict__ xp)
{
    const int bid = blockIdx.x;            // 256 * 24
    const int mt = bid / 24, nt = bid % 24;
    const int tid = threadIdx.x;
    const int w = tid >> 6, l = tid & 63;
    const int q = l >> 4, col = l & 15;
    const int M0 = mt * 128 + (w >> 1) * 64;
    const int N0 = nt * 128 + (w & 1) * 64;

    const u16* arow[4];
#pragma unroll
    for (int ai = 0; ai < 4; ++ai) {
        const int tok = seq[M0 + ai * 16 + col];
        arow[ai] = embb + (long)tok * E_;
    }
    const u16* brow[4];
#pragma unroll
    for (int bi = 0; bi < 4; ++bi)
        brow[bi] = wihbb + (long)(N0 + bi * 16 + col) * E_;

    f32x4 acc[4][4];
#pragma unroll
    for (int ai = 0; ai < 4; ++ai)
#pragma unroll
        for (int bi = 0; bi < 4; ++bi) acc[ai][bi] = (f32x4){0,0,0,0};

    for (int k = 0; k < 16; ++k) {
        const int ko = k * 32 + q * 8;
        short8 a[4], b[4];
#pragma unroll
        for (int ai = 0; ai < 4; ++ai) a[ai] = *(const short8*)(arow[ai] + ko);
#pragma unroll
        for (int bi = 0; bi < 4; ++bi) b[bi] = *(const short8*)(brow[bi] + ko);
#pragma unroll
        for (int ai = 0; ai < 4; ++ai)
#pragma unroll
            for (int bi = 0; bi < 4; ++bi)
                acc[ai][bi] = mfma16(a[ai], b[bi], acc[ai][bi]);
    }

#pragma unroll
    for (int bi = 0; bi < 4; ++bi) {
        const int n = N0 + bi * 16 + col;
        const int dir = (n >= 1536) ? 1 : 0;
        const int j = n - dir * 1536;
        const int g = j >> 9, u = j & 511, uc = u >> 4;
        const float bias = dir ? b_ih_b[j] : b_ih_f[j];
        const long base = (long)(dir * 32 + uc) * (64L * 512 * 48) + g * 16 + col;
#pragma unroll
        for (int ai = 0; ai < 4; ++ai) {
#pragma unroll
            for (int i = 0; i < 4; ++i) {
                const int m = M0 + ai * 16 + q * 4 + i;
                const int bs = m >> 9, s = m & 511;
                xp[base + ((long)bs * 512 + s) * 48] = f2bf(acc[ai][bi][i] + bias);
            }
        }
    }
}

// ---------- recurrence + fused segment max ----------
// 256 wgs of 64 threads (1 wave each) = 2 dirs x 4 sample-groups x 32 chunks.
// Barrier domain = (dir, group): 32 wave-flags in one 128B line. Arrival =
// relaxed store after s_waitcnt vmcnt(0); detection = lanes 0..31 poll + ballot.
// Change vs 2582-us baseline: NO acquire fence (it invalidated L1+L2 every
// step, forcing W_hh/xp/layout refetches from L3/HBM). Instead the h loads
// themselves bypass L1/L2 with sc0 sc1 (read at L3, the system coherence
// point where the writers' sc0 sc1 stores were drained before flag publish).
// All asm load outputs are EARLY-CLOBBER (=&v) — a plain =v may alias the
// address register pair and corrupt it on writeback (root cause of the two
// failed rounds).
__global__ __launch_bounds__(64, 1) void rnn_kernel(
    const int* __restrict__ lens, const int* __restrict__ layout,
    const u16* __restrict__ whhbb,
    const float* __restrict__ b_hh_f, const float* __restrict__ b_hh_b,
    const u16* __restrict__ xp, u16* __restrict__ hbuf, int* __restrict__ cnt,
    float* __restrict__ out)
{
    const int bid = blockIdx.x;            // 256 = dir(2) x group(4) x chunk(32)
    const int dir = bid >> 7;
    const int g   = (bid >> 5) & 3;
    const int uc  = bid & 31;
    const int u0  = uc * 16;
    const int l = threadIdx.x;             // one wave
    const int q = l >> 4, col = l & 15;
    const int u = u0 + col;

    // preload this wave's W_hh slice as MFMA B-fragments: 16 ksteps x 3 gates
    const u16* Whh = whhbb + (long)dir * (3 * H_ * H_);
    short8 wreg[16][3];
#pragma unroll
    for (int k = 0; k < 16; ++k)
#pragma unroll
        for (int gg = 0; gg < 3; ++gg)
            wreg[k][gg] = *(const short8*)(Whh + (long)(gg * 512 + u0 + col) * H_ + k * 32 + q * 8);

    const float* bhh = dir ? b_hh_b : b_hh_f;
    const float bh0 = bhh[0 * 512 + u];
    const float bh1 = bhh[1 * 512 + u];
    const float bh2 = bhh[2 * 512 + u];

    int samp[4], Ls[4], seg[4], bnd[4];
    float hm[4], mx[4];
    bool done[4];
#pragma unroll
    for (int i = 0; i < 4; ++i) {
        samp[i] = g * 16 + q * 4 + i;
        Ls[i] = lens[samp[i]];
        hm[i] = 0.f;
        mx[i] = -3.4e38f;
        done[i] = false;
        if (dir == 0) { seg[i] = 0; bnd[i] = layout[samp[i] * 65 + 1]; }
        else          { seg[i] = 63; bnd[i] = layout[samp[i] * 65 + 63]; }
    }
    const int asamp = g * 16 + col;        // A-fragment row (sample)

    const u16* xpb = xp + (long)(dir * 32 + uc) * (64L * 512 * 48);
    u16* hb_base = hbuf + (long)dir * 2 * B_ * H_;
    int* fl = cnt + (dir * 4 + g) * 32;    // 32 wave-flags, one cacheline

    // xp gate inputs for the CURRENT step (software-pipelined)
    u16 cxr[4], cxz[4], cxn[4];
    int cpv[4]; bool cval[4];
#pragma unroll
    for (int i = 0; i < 4; ++i) {
        const int L = Ls[i];
        cval[i] = (0 < L);
        int p = dir ? (L - 1) : 0;
        if (p < 0) p = 0;
        cpv[i] = p;
        const u16* xq = xpb + ((long)samp[i] * 512 + p) * 48;
        cxr[i] = xq[0 * 16 + col];
        cxz[i] = xq[1 * 16 + col];
        cxn[i] = xq[2 * 16 + col];
    }

    for (int t = 0; t < 512; ++t) {
        if (t > 0) {
            // wait for all 32 waves of this (dir,group) domain: flags >= t
            unsigned long long rdy;
            do {
                const int v = __hip_atomic_load(&fl[l & 31], __ATOMIC_RELAXED,
                                                __HIP_MEMORY_SCOPE_SYSTEM);
                rdy = __ballot((l >= 32) || (v >= t));
                if (rdy != ~0ULL) __builtin_amdgcn_s_sleep(1);
            } while (rdy != ~0ULL);
            // NO acquire fence: h loads below bypass L1/L2 directly.
        }

        // h loads: sc0 sc1 = read at L3 (system coherence point), fresh by
        // protocol. Early-clobber outputs; single shared base + imm offsets.
        const u16* hr = hb_base + (long)(t & 1) * B_ * H_ + (long)asamp * H_ + q * 8;
        short8 afrag[16];
        asm volatile("global_load_dwordx4 %0, %1, off sc0 sc1"             : "=&v"(afrag[0])  : "v"(hr));
        asm volatile("global_load_dwordx4 %0, %1, off offset:64 sc0 sc1"   : "=&v"(afrag[1])  : "v"(hr));
        asm volatile("global_load_dwordx4 %0, %1, off offset:128 sc0 sc1"  : "=&v"(afrag[2])  : "v"(hr));
        asm volatile("global_load_dwordx4 %0, %1, off offset:192 sc0 sc1"  : "=&v"(afrag[3])  : "v"(hr));
        asm volatile("global_load_dwordx4 %0, %1, off offset:256 sc0 sc1"  : "=&v"(afrag[4])  : "v"(hr));
        asm volatile("global_load_dwordx4 %0, %1, off offset:320 sc0 sc1"  : "=&v"(afrag[5])  : "v"(hr));
        asm volatile("global_load_dwordx4 %0, %1, off offset:384 sc0 sc1"  : "=&v"(afrag[6])  : "v"(hr));
        asm volatile("global_load_dwordx4 %0, %1, off offset:448 sc0 sc1"  : "=&v"(afrag[7])  : "v"(hr));
        asm volatile("global_load_dwordx4 %0, %1, off offset:512 sc0 sc1"  : "=&v"(afrag[8])  : "v"(hr));
        asm volatile("global_load_dwordx4 %0, %1, off offset:576 sc0 sc1"  : "=&v"(afrag[9])  : "v"(hr));
        asm volatile("global_load_dwordx4 %0, %1, off offset:640 sc0 sc1"  : "=&v"(afrag[10]) : "v"(hr));
        asm volatile("global_load_dwordx4 %0, %1, off offset:704 sc0 sc1"  : "=&v"(afrag[11]) : "v"(hr));
        asm volatile("global_load_dwordx4 %0, %1, off offset:768 sc0 sc1"  : "=&v"(afrag[12]) : "v"(hr));
        asm volatile("global_load_dwordx4 %0, %1, off offset:832 sc0 sc1"  : "=&v"(afrag[13]) : "v"(hr));
        asm volatile("global_load_dwordx4 %0, %1, off offset:896 sc0 sc1"  : "=&v"(afrag[14]) : "v"(hr));
        asm volatile("global_load_dwordx4 %0, %1, off offset:960 sc0 sc1"  : "=&v"(afrag[15]) : "v"(hr));

        // xp prefetch for t+1 issued while the h loads are in flight
        u16 nxr[4], nxz[4], nxn[4];
        int npv[4]; bool nval[4];
        const int tn = t + 1;
        if (tn < 512) {
#pragma unroll
            for (int i = 0; i < 4; ++i) {
                const int L = Ls[i];
                nval[i] = (tn < L);
                int p = dir ? (L - 1 - tn) : tn;
                if (p < 0) p = 0;
                npv[i] = p;
                const u16* xq = xpb + ((long)samp[i] * 512 + p) * 48;
                nxr[i] = xq[0 * 16 + col];
                nxz[i] = xq[1 * 16 + col];
                nxn[i] = xq[2 * 16 + col];
            }
        } else {
#pragma unroll
            for (int i = 0; i < 4; ++i) { nxr[i] = nxz[i] = nxn[i] = 0; npv[i] = 0; nval[i] = false; }
        }

        // all loads (h + prefetch) retired before MFMA consumes afrag
        asm volatile("s_waitcnt vmcnt(0)" ::: "memory");
        __builtin_amdgcn_sched_barrier(0);   // rule #18: pin MFMA after the wait

        f32x4 ar = {0,0,0,0}, az = {0,0,0,0}, an = {0,0,0,0};
#pragma unroll
        for (int k = 0; k < 16; ++k) {
            ar = mfma16(afrag[k], wreg[k][0], ar);
            az = mfma16(afrag[k], wreg[k][1], az);
            an = mfma16(afrag[k], wreg[k][2], an);
        }

        // gates + state update (critical path)
        float hnv[4];
#pragma unroll
        for (int i = 0; i < 4; ++i) {
            const float r = sigmoidf_(bf2f(cxr[i]) + ar[i] + bh0);
            const float z = sigmoidf_(bf2f(cxz[i]) + az[i] + bh1);
            const float n = tanhf_(bf2f(cxn[i]) + r * (an[i] + bh2));
            const float hnew = (1.f - z) * n + z * hm[i];
            if (cval[i]) hm[i] = hnew;
            hnv[i] = hnew;
        }

        // packed write-through h store (chain-critical)
        u16* hw = hb_base + (long)((t + 1) & 1) * B_ * H_;
#pragma unroll
        for (int i = 0; i < 4; ++i) {
            const float other = __shfl_xor(hm[i], 1);
            if ((col & 1) == 0) {
                const unsigned int pk = ((unsigned int)f2bf(other) << 16) | (unsigned int)f2bf(hm[i]);
                __hip_atomic_store((unsigned int*)(hw + (long)samp[i] * H_ + u), pk,
                                   __ATOMIC_RELAXED, __HIP_MEMORY_SCOPE_SYSTEM);
            }
        }

        // drain own stores, then publish
        asm volatile("s_waitcnt vmcnt(0)" ::: "memory");
        if (l == 0)
            __hip_atomic_store(&fl[uc], t + 1, __ATOMIC_RELAXED, __HIP_MEMORY_SCOPE_SYSTEM);

        // off-chain: fused ragged segment-max bookkeeping (after publish)
#pragma unroll
        for (int i = 0; i < 4; ++i) {
            if (cval[i]) {
                if (dir == 0) {
                    while (t >= bnd[i] && seg[i] < 63) {
                        out[((long)samp[i] * 64 + seg[i]) * 1024 + u] = mx[i];
                        seg[i]++;
                        bnd[i] = layout[samp[i] * 65 + seg[i] + 1];
                        mx[i] = -3.4e38f;
                    }
                } else {
                    while (cpv[i] < bnd[i] && seg[i] > 0) {
                        out[((long)samp[i] * 64 + seg[i]) * 1024 + 512 + u] = mx[i];
                        seg[i]--;
                        bnd[i] = layout[samp[i] * 65 + seg[i]];
                        mx[i] = -3.4e38f;
                    }
                }
                mx[i] = fmaxf(mx[i], hnv[i]);
            } else if (!done[i]) {
                out[((long)samp[i] * 64 + seg[i]) * 1024 + dir * 512 + u] = mx[i];
                done[i] = true;
            }
        }

        // rotate pipelined xp regs
#pragma unroll
        for (int i = 0; i < 4; ++i) {
            cxr[i] = nxr[i]; cxz[i] = nxz[i]; cxn[i] = nxn[i];
            cpv[i] = npv[i]; cval[i] = nval[i];
        }
    }

#pragma unroll
    for (int i = 0; i < 4; ++i) {
        if (!done[i])  // full-length samples: flush last segment
            out[((long)samp[i] * 64 + seg[i]) * 1024 + dir * 512 + u] = mx[i];
        // final hidden: out[4194304 + dir*B*H + b*H + u]
        out[4194304 + dir * (B_ * H_) + samp[i] * H_ + u] = hm[i];
    }
}

// ---------- launch ----------
extern "C" void kernel_launch(void* const* d_in, const int* in_sizes, int n_in,
                              void* d_out, int out_size, void* d_ws, size_t ws_size,
                              hipStream_t stream) {
    const int*   seq    = (const int*)d_in[0];
    const int*   lens   = (const int*)d_in[1];
    const int*   layout = (const int*)d_in[3];
    const float* emb    = (const float*)d_in[4];
    const float* w_ih_f = (const float*)d_in[5];
    const float* w_hh_f = (const float*)d_in[6];
    const float* b_ih_f = (const float*)d_in[7];
    const float* b_hh_f = (const float*)d_in[8];
    const float* w_ih_b = (const float*)d_in[9];
    const float* w_hh_b = (const float*)d_in[10];
    const float* b_ih_b = (const float*)d_in[11];
    const float* b_hh_b = (const float*)d_in[12];
    float* out = (float*)d_out;
    char* ws = (char*)d_ws;

    u16* embb  = (u16*)(ws + EMBB_OFF);
    u16* wihbb = (u16*)(ws + WIHB_OFF);
    u16* whhbb = (u16*)(ws + WHHB_OFF);
    u16* hbuf  = (u16*)(ws + HBUF_OFF);
    int* cnt   = (int*)(ws + CNT_OFF);
    u16* xp    = (u16*)(ws + XP_OFF);

    prep_kernel<<<2048, 256, 0, stream>>>(emb, w_ih_f, w_hh_f, w_ih_b, w_hh_b,
                                          embb, wihbb, whhbb, hbuf, cnt);
    proj_kernel<<<256 * 24, 256, 0, stream>>>(seq, embb, wihbb, b_ih_f, b_ih_b, xp);
    rnn_kernel<<<256, 64, 0, stream>>>(lens, layout, whhbb, b_hh_f, b_hh_b,
                                       xp, hbuf, cnt, out);
}

// Round 8
// 2305.540 us; speedup vs baseline: 9.9944x; 1.0152x over previous
//
#include <hip/hip_runtime.h>

typedef unsigned short u16;
typedef __attribute__((ext_vector_type(8))) short short8;
typedef __attribute__((ext_vector_type(4))) short short4v;
typedef __attribute__((ext_vector_type(4))) float f32x4;

#define B_    64
#define S_    512
#define E_    512
#define H_    512
#define NSEG_ 64

// ---------- helpers ----------
__device__ __forceinline__ float bf2f(u16 u) {
    union { unsigned int i; float f; } x; x.i = ((unsigned int)u) << 16; return x.f;
}
__device__ __forceinline__ u16 f2bf(float f) {
    union { float f; unsigned int i; } x; x.f = f;
    unsigned int r = x.i + 0x7fffu + ((x.i >> 16) & 1u);
    return (u16)(r >> 16);
}
__device__ __forceinline__ f32x4 mfma16(short8 a, short8 b, f32x4 c) {
    return __builtin_amdgcn_mfma_f32_16x16x32_bf16(a, b, c, 0, 0, 0);
}
__device__ __forceinline__ float sigmoidf_(float x) { return 1.f / (1.f + __expf(-x)); }
__device__ __forceinline__ float tanhf_(float x) {
    float e = __expf(-2.f * fabsf(x));
    float t = (1.f - e) / (1.f + e);
    return x < 0.f ? -t : t;
}

// workspace layout (bytes) — all inputs are FP32; bf16 copies live in ws.
#define EMBB_OFF  0
#define WIHB_OFF  51200000
#define WHHB_OFF  54345728
#define HBUF_OFF  57491456
#define CNT_OFF   57753600
#define XP_OFF    57757696

// ---------- prep: fp32 -> bf16 conversions + zero hbuf/flags ----------
__global__ __launch_bounds__(256) void prep_kernel(
    const float* __restrict__ emb,
    const float* __restrict__ wih_f, const float* __restrict__ whh_f,
    const float* __restrict__ wih_b, const float* __restrict__ whh_b,
    u16* __restrict__ embb, u16* __restrict__ wihbb, u16* __restrict__ whhbb,
    u16* __restrict__ hbuf, int* __restrict__ cnt)
{
    const int nt = gridDim.x * 256;
    const int i = blockIdx.x * 256 + threadIdx.x;

    const float4* e4 = (const float4*)emb;
    short4v* eo = (short4v*)embb;
    for (int k = i; k < 6400000; k += nt) {
        float4 v = e4[k];
        short4v o = { (short)f2bf(v.x), (short)f2bf(v.y), (short)f2bf(v.z), (short)f2bf(v.w) };
        eo[k] = o;
    }
    const float4* wf[4] = { (const float4*)wih_f, (const float4*)wih_b,
                            (const float4*)whh_f, (const float4*)whh_b };
    short4v* wo[4] = { (short4v*)wihbb, (short4v*)(wihbb + 786432),
                       (short4v*)whhbb, (short4v*)(whhbb + 786432) };
#pragma unroll
    for (int a = 0; a < 4; ++a) {
        for (int k = i; k < 196608; k += nt) {
            float4 v = wf[a][k];
            short4v o = { (short)f2bf(v.x), (short)f2bf(v.y), (short)f2bf(v.z), (short)f2bf(v.w) };
            wo[a][k] = o;
        }
    }
    int* hz = (int*)hbuf;
    for (int k = i; k < 65536; k += nt) hz[k] = 0;
    for (int k = i; k < 1024; k += nt) cnt[k] = 0;
}

// ---------- input projection: xp = emb[seq] @ w_ih_d^T + b_ih_d ----------
__global__ __launch_bounds__(256) void proj_kernel(
    const int* __restrict__ seq, const u16* __restrict__ embb,
    const u16* __restrict__ wihbb,
    const float* __restrict__ b_ih_f, const float* __restrict__ b_ih_b,
    u16* __restrict__ xp)
{
    const int bid = blockIdx.x;            // 256 * 24
    const int mt = bid / 24, nt = bid % 24;
    const int tid = threadIdx.x;
    const int w = tid >> 6, l = tid & 63;
    const int q = l >> 4, col = l & 15;
    const int M0 = mt * 128 + (w >> 1) * 64;
    const int N0 = nt * 128 + (w & 1) * 64;

    const u16* arow[4];
#pragma unroll
    for (int ai = 0; ai < 4; ++ai) {
        const int tok = seq[M0 + ai * 16 + col];
        arow[ai] = embb + (long)tok * E_;
    }
    const u16* brow[4];
#pragma unroll
    for (int bi = 0; bi < 4; ++bi)
        brow[bi] = wihbb + (long)(N0 + bi * 16 + col) * E_;

    f32x4 acc[4][4];
#pragma unroll
    for (int ai = 0; ai < 4; ++ai)
#pragma unroll
        for (int bi = 0; bi < 4; ++bi) acc[ai][bi] = (f32x4){0,0,0,0};

    for (int k = 0; k < 16; ++k) {
        const int ko = k * 32 + q * 8;
        short8 a[4], b[4];
#pragma unroll
        for (int ai = 0; ai < 4; ++ai) a[ai] = *(const short8*)(arow[ai] + ko);
#pragma unroll
        for (int bi = 0; bi < 4; ++bi) b[bi] = *(const short8*)(brow[bi] + ko);
#pragma unroll
        for (int ai = 0; ai < 4; ++ai)
#pragma unroll
            for (int bi = 0; bi < 4; ++bi)
                acc[ai][bi] = mfma16(a[ai], b[bi], acc[ai][bi]);
    }

#pragma unroll
    for (int bi = 0; bi < 4; ++bi) {
        const int n = N0 + bi * 16 + col;
        const int dir = (n >= 1536) ? 1 : 0;
        const int j = n - dir * 1536;
        const int g = j >> 9, u = j & 511, uc = u >> 4;
        const float bias = dir ? b_ih_b[j] : b_ih_f[j];
        const long base = (long)(dir * 32 + uc) * (64L * 512 * 48) + g * 16 + col;
#pragma unroll
        for (int ai = 0; ai < 4; ++ai) {
#pragma unroll
            for (int i = 0; i < 4; ++i) {
                const int m = M0 + ai * 16 + q * 4 + i;
                const int bs = m >> 9, s = m & 511;
                xp[base + ((long)bs * 512 + s) * 48] = f2bf(acc[ai][bi][i] + bias);
            }
        }
    }
}

// ---------- recurrence + fused segment max ----------
// Round-4 protocol VERBATIM (harness-proven at 2340us). SINGLE diff: W_hh is
// pinned via PLAIN loads + an empty opacifying asm per fragment. Plain loads
// keep all waits (including any spill) compiler-managed — round 7 proved that
// asm-LOADED values can be spilled before their wait (no compiler-known load
// => no inserted s_waitcnt => garbage spill, absmax 7e-2). The empty asm only
// forbids rematerialization, forcing the 192 weight VGPRs to stay resident.
__global__ __launch_bounds__(64, 1) void rnn_kernel(
    const int* __restrict__ lens, const int* __restrict__ layout,
    const u16* __restrict__ whhbb,
    const float* __restrict__ b_hh_f, const float* __restrict__ b_hh_b,
    const u16* __restrict__ xp, u16* __restrict__ hbuf, int* __restrict__ cnt,
    float* __restrict__ out)
{
    const int bid = blockIdx.x;            // 256 = dir(2) x group(4) x chunk(32)
    const int dir = bid >> 7;
    const int g   = (bid >> 5) & 3;
    const int uc  = bid & 31;
    const int u0  = uc * 16;
    const int l = threadIdx.x;             // one wave
    const int q = l >> 4, col = l & 15;
    const int u = u0 + col;

    // preload this wave's W_hh slice (plain loads — compiler-managed waits),
    // then make each fragment opaque so it cannot be rematerialized.
    const u16* Whh = whhbb + (long)dir * (3 * H_ * H_);
    short8 wreg[3][16];
#pragma unroll
    for (int gg = 0; gg < 3; ++gg) {
        const u16* wr = Whh + (long)(gg * 512 + u0 + col) * H_ + q * 8;
#pragma unroll
        for (int k = 0; k < 16; ++k)
            wreg[gg][k] = *(const short8*)(wr + k * 32);
    }
#pragma unroll
    for (int gg = 0; gg < 3; ++gg)
#pragma unroll
        for (int k = 0; k < 16; ++k)
            asm volatile("" : "+v"(wreg[gg][k]));

    const float* bhh = dir ? b_hh_b : b_hh_f;
    const float bh0 = bhh[0 * 512 + u];
    const float bh1 = bhh[1 * 512 + u];
    const float bh2 = bhh[2 * 512 + u];

    int samp[4], Ls[4], seg[4], bnd[4];
    float hm[4], mx[4];
    bool done[4];
#pragma unroll
    for (int i = 0; i < 4; ++i) {
        samp[i] = g * 16 + q * 4 + i;
        Ls[i] = lens[samp[i]];
        hm[i] = 0.f;
        mx[i] = -3.4e38f;
        done[i] = false;
        if (dir == 0) { seg[i] = 0; bnd[i] = layout[samp[i] * 65 + 1]; }
        else          { seg[i] = 63; bnd[i] = layout[samp[i] * 65 + 63]; }
    }
    const int asamp = g * 16 + col;        // A-fragment row (sample)

    const u16* xpb = xp + (long)(dir * 32 + uc) * (64L * 512 * 48);
    u16* hb_base = hbuf + (long)dir * 2 * B_ * H_;
    int* fl = cnt + (dir * 4 + g) * 32;    // 32 wave-flags, one cacheline

    // xp gate inputs for the CURRENT step (software-pipelined, plain loads)
    u16 cxr[4], cxz[4], cxn[4];
    int cpv[4]; bool cval[4];
#pragma unroll
    for (int i = 0; i < 4; ++i) {
        const int L = Ls[i];
        cval[i] = (0 < L);
        int p = dir ? (L - 1) : 0;
        if (p < 0) p = 0;
        cpv[i] = p;
        const u16* xq = xpb + ((long)samp[i] * 512 + p) * 48;
        cxr[i] = xq[0 * 16 + col];
        cxz[i] = xq[1 * 16 + col];
        cxn[i] = xq[2 * 16 + col];
    }

    for (int t = 0; t < 512; ++t) {
        if (t > 0) {
            // wait for all 32 waves of this (dir,group) domain: flags >= t
            unsigned long long rdy;
            do {
                const int v = __hip_atomic_load(&fl[l & 31], __ATOMIC_RELAXED,
                                                __HIP_MEMORY_SCOPE_SYSTEM);
                rdy = __ballot((l >= 32) || (v >= t));
                if (rdy != ~0ULL) __builtin_amdgcn_s_sleep(1);
            } while (rdy != ~0ULL);
            // NO acquire fence: h loads below bypass L1/L2 directly.
        }

        // h loads: sc0 sc1 = read at L3 (system coherence point), fresh by
        // protocol. Early-clobber outputs; consumed ONLY after the explicit
        // vmcnt(0) below (never copied early) — proven safe in two passes.
        const u16* hr = hb_base + (long)(t & 1) * B_ * H_ + (long)asamp * H_ + q * 8;
        short8 afrag[16];
        asm volatile("global_load_dwordx4 %0, %1, off sc0 sc1"             : "=&v"(afrag[0])  : "v"(hr));
        asm volatile("global_load_dwordx4 %0, %1, off offset:64 sc0 sc1"   : "=&v"(afrag[1])  : "v"(hr));
        asm volatile("global_load_dwordx4 %0, %1, off offset:128 sc0 sc1"  : "=&v"(afrag[2])  : "v"(hr));
        asm volatile("global_load_dwordx4 %0, %1, off offset:192 sc0 sc1"  : "=&v"(afrag[3])  : "v"(hr));
        asm volatile("global_load_dwordx4 %0, %1, off offset:256 sc0 sc1"  : "=&v"(afrag[4])  : "v"(hr));
        asm volatile("global_load_dwordx4 %0, %1, off offset:320 sc0 sc1"  : "=&v"(afrag[5])  : "v"(hr));
        asm volatile("global_load_dwordx4 %0, %1, off offset:384 sc0 sc1"  : "=&v"(afrag[6])  : "v"(hr));
        asm volatile("global_load_dwordx4 %0, %1, off offset:448 sc0 sc1"  : "=&v"(afrag[7])  : "v"(hr));
        asm volatile("global_load_dwordx4 %0, %1, off offset:512 sc0 sc1"  : "=&v"(afrag[8])  : "v"(hr));
        asm volatile("global_load_dwordx4 %0, %1, off offset:576 sc0 sc1"  : "=&v"(afrag[9])  : "v"(hr));
        asm volatile("global_load_dwordx4 %0, %1, off offset:640 sc0 sc1"  : "=&v"(afrag[10]) : "v"(hr));
        asm volatile("global_load_dwordx4 %0, %1, off offset:704 sc0 sc1"  : "=&v"(afrag[11]) : "v"(hr));
        asm volatile("global_load_dwordx4 %0, %1, off offset:768 sc0 sc1"  : "=&v"(afrag[12]) : "v"(hr));
        asm volatile("global_load_dwordx4 %0, %1, off offset:832 sc0 sc1"  : "=&v"(afrag[13]) : "v"(hr));
        asm volatile("global_load_dwordx4 %0, %1, off offset:896 sc0 sc1"  : "=&v"(afrag[14]) : "v"(hr));
        asm volatile("global_load_dwordx4 %0, %1, off offset:960 sc0 sc1"  : "=&v"(afrag[15]) : "v"(hr));

        // xp prefetch for t+1 issued while the h loads are in flight
        // (plain loads — compiler manages their waits and copies correctly)
        u16 nxr[4], nxz[4], nxn[4];
        int npv[4]; bool nval[4];
        const int tn = t + 1;
        if (tn < 512) {
#pragma unroll
            for (int i = 0; i < 4; ++i) {
                const int L = Ls[i];
                nval[i] = (tn < L);
                int p = dir ? (L - 1 - tn) : tn;
                if (p < 0) p = 0;
                npv[i] = p;
                const u16* xq = xpb + ((long)samp[i] * 512 + p) * 48;
                nxr[i] = xq[0 * 16 + col];
                nxz[i] = xq[1 * 16 + col];
                nxn[i] = xq[2 * 16 + col];
            }
        } else {
#pragma unroll
            for (int i = 0; i < 4; ++i) { nxr[i] = nxz[i] = nxn[i] = 0; npv[i] = 0; nval[i] = false; }
        }

        // all loads (h + prefetch) retired before MFMA consumes afrag
        asm volatile("s_waitcnt vmcnt(0)" ::: "memory");
        __builtin_amdgcn_sched_barrier(0);   // rule #18: pin MFMA after the wait

        f32x4 ar = {0,0,0,0}, az = {0,0,0,0}, an = {0,0,0,0};
#pragma unroll
        for (int k = 0; k < 16; ++k) {
            ar = mfma16(afrag[k], wreg[0][k], ar);
            az = mfma16(afrag[k], wreg[1][k], az);
            an = mfma16(afrag[k], wreg[2][k], an);
        }

        // gates + state update (critical path)
        float hnv[4];
#pragma unroll
        for (int i = 0; i < 4; ++i) {
            const float r = sigmoidf_(bf2f(cxr[i]) + ar[i] + bh0);
            const float z = sigmoidf_(bf2f(cxz[i]) + az[i] + bh1);
            const float n = tanhf_(bf2f(cxn[i]) + r * (an[i] + bh2));
            const float hnew = (1.f - z) * n + z * hm[i];
            if (cval[i]) hm[i] = hnew;
            hnv[i] = hnew;
        }

        // packed write-through h store (chain-critical)
        u16* hw = hb_base + (long)((t + 1) & 1) * B_ * H_;
#pragma unroll
        for (int i = 0; i < 4; ++i) {
            const float other = __shfl_xor(hm[i], 1);
            if ((col & 1) == 0) {
                const unsigned int pk = ((unsigned int)f2bf(other) << 16) | (unsigned int)f2bf(hm[i]);
                __hip_atomic_store((unsigned int*)(hw + (long)samp[i] * H_ + u), pk,
                                   __ATOMIC_RELAXED, __HIP_MEMORY_SCOPE_SYSTEM);
            }
        }

        // drain own stores, then publish
        asm volatile("s_waitcnt vmcnt(0)" ::: "memory");
        if (l == 0)
            __hip_atomic_store(&fl[uc], t + 1, __ATOMIC_RELAXED, __HIP_MEMORY_SCOPE_SYSTEM);

        // off-chain: fused ragged segment-max bookkeeping (after publish)
#pragma unroll
        for (int i = 0; i < 4; ++i) {
            if (cval[i]) {
                if (dir == 0) {
                    while (t >= bnd[i] && seg[i] < 63) {
                        out[((long)samp[i] * 64 + seg[i]) * 1024 + u] = mx[i];
                        seg[i]++;
                        bnd[i] = layout[samp[i] * 65 + seg[i] + 1];
                        mx[i] = -3.4e38f;
                    }
                } else {
                    while (cpv[i] < bnd[i] && seg[i] > 0) {
                        out[((long)samp[i] * 64 + seg[i]) * 1024 + 512 + u] = mx[i];
                        seg[i]--;
                        bnd[i] = layout[samp[i] * 65 + seg[i]];
                        mx[i] = -3.4e38f;
                    }
                }
                mx[i] = fmaxf(mx[i], hnv[i]);
            } else if (!done[i]) {
                out[((long)samp[i] * 64 + seg[i]) * 1024 + dir * 512 + u] = mx[i];
                done[i] = true;
            }
        }

        // rotate pipelined xp regs
#pragma unroll
        for (int i = 0; i < 4; ++i) {
            cxr[i] = nxr[i]; cxz[i] = nxz[i]; cxn[i] = nxn[i];
            cpv[i] = npv[i]; cval[i] = nval[i];
        }
    }

#pragma unroll
    for (int i = 0; i < 4; ++i) {
        if (!done[i])  // full-length samples: flush last segment
            out[((long)samp[i] * 64 + seg[i]) * 1024 + dir * 512 + u] = mx[i];
        // final hidden: out[4194304 + dir*B*H + b*H + u]
        out[4194304 + dir * (B_ * H_) + samp[i] * H_ + u] = hm[i];
    }
}

// ---------- launch ----------
extern "C" void kernel_launch(void* const* d_in, const int* in_sizes, int n_in,
                              void* d_out, int out_size, void* d_ws, size_t ws_size,
                              hipStream_t stream) {
    const int*   seq    = (const int*)d_in[0];
    const int*   lens   = (const int*)d_in[1];
    const int*   layout = (const int*)d_in[3];
    const float* emb    = (const float*)d_in[4];
    const float* w_ih_f = (const float*)d_in[5];
    const float* w_hh_f = (const float*)d_in[6];
    const float* b_ih_f = (const float*)d_in[7];
    const float* b_hh_f = (const float*)d_in[8];
    const float* w_ih_b = (const float*)d_in[9];
    const float* w_hh_b = (const float*)d_in[10];
    const float* b_ih_b = (const float*)d_in[11];
    const float* b_hh_b = (const float*)d_in[12];
    float* out = (float*)d_out;
    char* ws = (char*)d_ws;

    u16* embb  = (u16*)(ws + EMBB_OFF);
    u16* wihbb = (u16*)(ws + WIHB_OFF);
    u16* whhbb = (u16*)(ws + WHHB_OFF);
    u16* hbuf  = (u16*)(ws + HBUF_OFF);
    int* cnt   = (int*)(ws + CNT_OFF);
    u16* xp    = (u16*)(ws + XP_OFF);

    prep_kernel<<<2048, 256, 0, stream>>>(emb, w_ih_f, w_hh_f, w_ih_b, w_hh_b,
                                          embb, wihbb, whhbb, hbuf, cnt);
    proj_kernel<<<256 * 24, 256, 0, stream>>>(seq, embb, wihbb, b_ih_f, b_ih_b, xp);
    rnn_kernel<<<256, 64, 0, stream>>>(lens, layout, whhbb, b_hh_f, b_hh_b,
                                       xp, hbuf, cnt, out);
}